// Round 9
// baseline (123.488 us; speedup 1.0000x reference)
//
#include <hip/hip_runtime.h>
#include <hip/hip_bf16.h>
#include <math.h>

typedef _Float16 f16x8 __attribute__((ext_vector_type(8)));
typedef _Float16 f16x4 __attribute__((ext_vector_type(4)));
typedef __fp16   hf4  __attribute__((ext_vector_type(4)));
typedef float    f32x4 __attribute__((ext_vector_type(4)));
typedef __bf16   bf16x8 __attribute__((ext_vector_type(8)));
typedef __bf16   bf16x4 __attribute__((ext_vector_type(4)));

#define MFMA32_F16(a,b,c)  __builtin_amdgcn_mfma_f32_16x16x32_f16((a),(b),(c),0,0,0)
#define MFMA_BF16(a,b,c)   __builtin_amdgcn_mfma_f32_16x16x32_bf16((a),(b),(c),0,0,0)

constexpr int S_LEN = 2048;
constexpr int DH    = 64;
constexpr int KBLK  = 32;                 // kv rows per tile
constexpr int NSTEP = S_LEN / KBLK;       // 64
constexpr float LOG2E = 1.44269504088896340736f;
constexpr size_t TILE_BYTES = 8192;       // 4KB K + 4KB V-frag per tile
constexpr size_t WS_NEED = 64ull * NSTEP * TILE_BYTES;  // 33.55 MB

__device__ __forceinline__ void gload16(const void* g, void* l) {
    __builtin_amdgcn_global_load_lds(
        (const __attribute__((address_space(1))) void*)g,
        (__attribute__((address_space(3))) void*)l, 16, 0, 0);
}

__device__ __forceinline__ float exp2_fast(float x) {
    float r;
    asm("v_exp_f32 %0, %1" : "=v"(r) : "v"(x));
    return r;
}

// reductions across the 4 lane-groups holding one q-row (l^16, l^32)
__device__ __forceinline__ float redmax_lg(float x) {
    x = fmaxf(x, __shfl_xor(x, 16));
    x = fmaxf(x, __shfl_xor(x, 32));
    return x;
}
__device__ __forceinline__ float redadd_lg(float x) {
    x += __shfl_xor(x, 16);
    x += __shfl_xor(x, 32);
    return x;
}

__device__ __forceinline__ f16x4 as_f16x4(hf4 h) {
    f16x4 f;
    __builtin_memcpy(&f, &h, 8);
    return f;
}

// ---------------- pre-pass: K -> fp16 swizzled rows; V -> permuted-k A-fragments ----------------
// per (bh,tile) of 32 kv rows:
// K (4KB): row-major, byte (row*128 + d*2) ^ ((row&7)<<4)
// V (4KB): chunk16B[lg*1024 + d*16]: halves[j] = V[(j>>2)*16 + lg*4 + (j&3)][d]
//   == A-fragment of 16x16x32 MFMA under shared k-map k(lg,j) = (j>>2)*16 + lg*4 + (j&3)
__global__ __launch_bounds__(256)
void prep_kernel(const float* __restrict__ Kg, const float* __restrict__ Vg,
                 unsigned char* __restrict__ ws)
{
    __shared__ _Float16 sT[32 * 70];   // V tile staging, pitch 70 halfs

    const int blk = blockIdx.x;        // bh*64 + tile
    const int tid = threadIdx.x;
    const float* Kt = Kg + (size_t)blk * KBLK * DH;
    const float* Vt = Vg + (size_t)blk * KBLK * DH;
    char* wK = (char*)(ws + (size_t)blk * TILE_BYTES);
    char* wV = wK + 4096;

    {
        const int row = tid >> 3;          // 0..31
        const int d0  = (tid & 7) * 8;
        // K: convert + pre-swizzled row-major tile
        f32x4 a = *(const f32x4*)(Kt + row * DH + d0);
        f32x4 b = *(const f32x4*)(Kt + row * DH + d0 + 4);
        f16x8 h;
        #pragma unroll
        for (int j = 0; j < 4; ++j) { h[j] = (_Float16)a[j]; h[4 + j] = (_Float16)b[j]; }
        const int koff = (row * 128 + d0 * 2) ^ ((row & 7) << 4);
        *(f16x8*)(wK + koff) = h;
        // V: convert into LDS row-major (pitch 70)
        f32x4 va = *(const f32x4*)(Vt + row * DH + d0);
        f32x4 vb = *(const f32x4*)(Vt + row * DH + d0 + 4);
        #pragma unroll
        for (int j = 0; j < 4; ++j) {
            sT[row * 70 + d0 + j]     = (_Float16)va[j];
            sT[row * 70 + d0 + 4 + j] = (_Float16)vb[j];
        }
    }
    __syncthreads();
    // build permuted-k V-fragment chunks (256 chunks, 1/thread)
    {
        const int lgc = (tid >> 6) & 3;    // 0..3
        const int d   = tid & 63;
        f16x8 h;
        #pragma unroll
        for (int j = 0; j < 4; ++j) {
            h[j]     = sT[(lgc * 4 + j) * 70 + d];
            h[4 + j] = sT[(16 + lgc * 4 + j) * 70 + d];
        }
        *(f16x8*)(wV + lgc * 1024 + d * 16) = h;
    }
}

// ---------------- main: flash attention, 1 q-tile/block, KBLK=32, 8 blocks/CU ----------------
__global__ __launch_bounds__(256, 8)
void attn_main(const float* __restrict__ Qg0, const unsigned char* __restrict__ ws,
               float* __restrict__ Og0)
{
    __shared__ __align__(16) _Float16 sK[2][KBLK * DH];   // 2 x 4KB
    __shared__ __align__(16) _Float16 sV[2][KBLK * DH];   // 2 x 4KB (total 16384)

    const int tid  = threadIdx.x;
    const int lane = tid & 63;
    const int w    = tid >> 6;
    const int lg   = lane >> 4;
    const int li   = lane & 15;
    const int X    = (li & 7) << 4;    // K-read XOR swizzle key

    // 2048 blocks = 8 xcd * 8 bh * 32 qtiles
    const int n   = blockIdx.x;
    const int xcd = n & 7;
    const int m_  = n >> 3;            // 0..255
    const int bh  = xcd * 8 + (m_ >> 5);
    const int qt  = m_ & 31;

    const float* Qg = Qg0 + (size_t)bh * S_LEN * DH;
    float*       Og = Og0 + (size_t)bh * S_LEN * DH;
    const unsigned char* wsb = ws + (size_t)bh * NSTEP * TILE_BYTES;

    // Q fragments (fp16), pre-scaled by log2(e)
    f16x8 q[2];
    {
        const int qrow = qt * 64 + w * 16 + li;
        const float* qp = Qg + (size_t)qrow * DH;
        #pragma unroll
        for (int f = 0; f < 2; ++f) {
            f32x4 a0 = *(const f32x4*)(qp + f * 32 + lg * 8);
            f32x4 a1 = *(const f32x4*)(qp + f * 32 + lg * 8 + 4);
            #pragma unroll
            for (int j = 0; j < 4; ++j) {
                q[f][j]     = (_Float16)(a0[j] * LOG2E);
                q[f][4 + j] = (_Float16)(a1[j] * LOG2E);
            }
        }
    }

    f32x4 acco[4];
    #pragma unroll
    for (int t = 0; t < 4; ++t) acco[t] = f32x4{0.f, 0.f, 0.f, 0.f};
    // running max (row-uniform, log2 domain, init 0); lane-LOCAL partial denominator
    float m = 0.f, l = 0.f;

    auto stage = [&](int buf, int t) {
        const unsigned char* src = wsb + (size_t)t * TILE_BYTES;
        gload16(src + w * 1024 + lane * 16,        (char*)&sK[buf][0] + w * 1024);
        gload16(src + 4096 + w * 1024 + lane * 16, (char*)&sV[buf][0] + w * 1024);
    };

    stage(0, 0);
    __syncthreads();
    int buf = 0;

    for (int t = 0; t < NSTEP; ++t) {
        if (t + 1 < NSTEP) stage(buf ^ 1, t + 1);

        const char* kb = (const char*)&sK[buf][0];
        const char* vb = (const char*)&sV[buf][0];

        // ---- S^T - m = K Q^T + (-m) : s[t4][r] = S^T[kv=t4*16+lg*4+r][q=li] - m ----
        const f32x4 cI = {-m, -m, -m, -m};
        f32x4 s0, s1;
        __builtin_amdgcn_s_setprio(1);
        {
            const char* kr0 = kb + li * 128;
            const char* kr1 = kb + 2048 + li * 128;
            f16x8 k00 = *(const f16x8*)(kr0 + ((lg * 16) ^ X));
            f16x8 k01 = *(const f16x8*)(kr0 + ((64 + lg * 16) ^ X));
            f16x8 k10 = *(const f16x8*)(kr1 + ((lg * 16) ^ X));
            f16x8 k11 = *(const f16x8*)(kr1 + ((64 + lg * 16) ^ X));
            s0 = MFMA32_F16(k00, q[0], cI);
            s0 = MFMA32_F16(k01, q[1], s0);
            s1 = MFMA32_F16(k10, q[0], cI);
            s1 = MFMA32_F16(k11, q[1], s1);
        }
        __builtin_amdgcn_s_setprio(0);

        // ---- lane-local max of biased scores (8 kv each) ----
        float ml = fmaxf(fmaxf(fmaxf(s0[0], s0[1]), fmaxf(s0[2], s0[3])),
                         fmaxf(fmaxf(s1[0], s1[1]), fmaxf(s1[2], s1[3])));

        // ---- defer-max rescale: fires rarely; re-bias scores when it does ----
        if (__any(ml > 8.f)) {
            const float rowmax = redmax_lg(ml);
            const float delta  = fmaxf(rowmax, 0.f);
            const float sc     = exp2_fast(-delta);
            m += delta;  l *= sc;
            #pragma unroll
            for (int t4 = 0; t4 < 4; ++t4) acco[t4] *= sc;
            s0 -= delta;  s1 -= delta;
        }

        // ---- exp2 + packed f16 convert; lane-local partial sum ----
        float a0 = exp2_fast(s0[0]);
        float a1 = exp2_fast(s0[1]);
        float a2 = exp2_fast(s0[2]);
        float a3 = exp2_fast(s0[3]);
        float b0 = exp2_fast(s1[0]);
        float b1 = exp2_fast(s1[1]);
        float b2 = exp2_fast(s1[2]);
        float b3 = exp2_fast(s1[3]);
        l += ((a0 + a1) + (a2 + a3)) + ((b0 + b1) + (b2 + b3));
        f16x4 p0 = as_f16x4(__builtin_shufflevector(
            __builtin_amdgcn_cvt_pkrtz(a0, a1),
            __builtin_amdgcn_cvt_pkrtz(a2, a3), 0, 1, 2, 3));
        f16x4 p1 = as_f16x4(__builtin_shufflevector(
            __builtin_amdgcn_cvt_pkrtz(b0, b1),
            __builtin_amdgcn_cvt_pkrtz(b2, b3), 0, 1, 2, 3));
        f16x8 pf = __builtin_shufflevector(p0, p1, 0, 1, 2, 3, 4, 5, 6, 7);

        // ---- O^T += V^T P^T  (K=32 MFMA, shared permuted k-map) ----
        __builtin_amdgcn_s_setprio(1);
        #pragma unroll
        for (int t4v = 0; t4v < 4; ++t4v) {
            f16x8 vv = *(const f16x8*)(vb + lg * 1024 + t4v * 256 + li * 16);
            acco[t4v] = MFMA32_F16(vv, pf, acco[t4v]);
        }
        __builtin_amdgcn_s_setprio(0);

        __syncthreads();
        buf ^= 1;
    }

    // ---- epilogue: reduce partial denominators, normalize, store ----
    {
        const float ltot = redadd_lg(l);
        const int qrow = qt * 64 + w * 16 + li;
        const float inv = 1.f / ltot;
        float* oa = Og + (size_t)qrow * DH;
        #pragma unroll
        for (int t4 = 0; t4 < 4; ++t4) {
            f32x4 o;
            #pragma unroll
            for (int r = 0; r < 4; ++r) o[r] = acco[t4][r] * inv;
            *(f32x4*)(oa + t4 * 16 + lg * 4) = o;
        }
    }
}

// ---------------- fallback (fp32-input, used only if ws too small) ----------------
__global__ __launch_bounds__(256)
void attn_fwd_kernel(const float* __restrict__ Qg0,
                     const float* __restrict__ Kg0,
                     const float* __restrict__ Vg0,
                     float* __restrict__ Og0)
{
    constexpr int FKB = 64;
    constexpr int FNS = S_LEN / FKB;
    constexpr int VT_P = 72;
    constexpr int P_PB = 72;
    __shared__ __align__(16) __bf16 sKh[FKB * DH];
    __shared__ __align__(16) __bf16 sKl[FKB * DH];
    __shared__ __align__(16) __bf16 sVt[DH * VT_P];
    __shared__ __align__(16) __bf16 sP[4][16 * P_PB];

    const int tid  = threadIdx.x;
    const int lane = tid & 63;
    const int w    = tid >> 6;
    const int lg   = lane >> 4;
    const int li   = lane & 15;

    const int n   = blockIdx.x;
    const int xcd = n & 7;
    const int m   = n >> 3;
    const int bh  = xcd * 8 + (m >> 5);
    const int qt  = m & 31;

    const float* Qg = Qg0 + (size_t)bh * S_LEN * DH;
    const float* Kg = Kg0 + (size_t)bh * S_LEN * DH;
    const float* Vg = Vg0 + (size_t)bh * S_LEN * DH;
    float*       Og = Og0 + (size_t)bh * S_LEN * DH;

    bf16x8 qh[2], ql[2];
    {
        const int qrow = qt * 64 + w * 16 + li;
        const float* qp = Qg + (size_t)qrow * DH;
        #pragma unroll
        for (int f = 0; f < 2; ++f) {
            const int dbase = f * 32 + lg * 8;
            #pragma unroll
            for (int j = 0; j < 8; ++j) {
                float q = qp[dbase + j];
                __bf16 h = (__bf16)q;
                qh[f][j] = h;
                ql[f][j] = (__bf16)(q - (float)h);
            }
        }
    }

    f32x4 acco[4];
    #pragma unroll
    for (int t = 0; t < 4; ++t) acco[t] = f32x4{0.f, 0.f, 0.f, 0.f};
    float mval[4], lval[4];
    #pragma unroll
    for (int r = 0; r < 4; ++r) { mval[r] = -INFINITY; lval[r] = 0.f; }

    for (int step = 0; step < FNS; ++step) {
        __syncthreads();
        {
            const int kv0 = step * FKB;
            #pragma unroll
            for (int i = 0; i < 4; ++i) {
                const int f4 = tid + i * 256;
                const int kv = f4 >> 4;
                const int d4 = (f4 & 15) << 2;
                f32x4 kvec = *(const f32x4*)(Kg + (size_t)(kv0 + kv) * DH + d4);
                bf16x4 h, l;
                #pragma unroll
                for (int j = 0; j < 4; ++j) {
                    __bf16 hh = (__bf16)kvec[j];
                    h[j] = hh;
                    l[j] = (__bf16)(kvec[j] - (float)hh);
                }
                const int idx = (kv * DH + d4) ^ ((kv & 7) << 3);
                *(bf16x4*)&sKh[idx] = h;
                *(bf16x4*)&sKl[idx] = l;
                f32x4 vvec = *(const f32x4*)(Vg + (size_t)(kv0 + kv) * DH + d4);
                #pragma unroll
                for (int j = 0; j < 4; ++j)
                    sVt[(d4 + j) * VT_P + kv] = (__bf16)vvec[j];
            }
        }
        __syncthreads();

        f32x4 accs[4];
        #pragma unroll
        for (int t4 = 0; t4 < 4; ++t4) {
            f32x4 acc = f32x4{0.f, 0.f, 0.f, 0.f};
            const int row = t4 * 16 + li;
            #pragma unroll
            for (int f = 0; f < 2; ++f) {
                const int idx = (row * DH + f * 32 + lg * 8) ^ ((row & 7) << 3);
                bf16x8 kh = *(const bf16x8*)&sKh[idx];
                bf16x8 kl = *(const bf16x8*)&sKl[idx];
                acc = MFMA_BF16(qh[f], kh, acc);
                acc = MFMA_BF16(qh[f], kl, acc);
                acc = MFMA_BF16(ql[f], kh, acc);
            }
            accs[t4] = acc;
        }

        #pragma unroll
        for (int r = 0; r < 4; ++r) {
            float mx = fmaxf(fmaxf(accs[0][r], accs[1][r]), fmaxf(accs[2][r], accs[3][r]));
            #pragma unroll
            for (int msk = 1; msk <= 8; msk <<= 1)
                mx = fmaxf(mx, __shfl_xor(mx, msk));
            const float newm  = fmaxf(mval[r], mx);
            const float scale = __expf(mval[r] - newm);
            mval[r] = newm;
            lval[r] *= scale;
            #pragma unroll
            for (int t4 = 0; t4 < 4; ++t4) acco[t4][r] *= scale;
            float s = 0.f;
            #pragma unroll
            for (int t4 = 0; t4 < 4; ++t4) {
                float p = __expf(accs[t4][r] - newm);
                accs[t4][r] = p;
                s += p;
            }
            #pragma unroll
            for (int msk = 1; msk <= 8; msk <<= 1)
                s += __shfl_xor(s, msk);
            lval[r] += s;
        }

        #pragma unroll
        for (int r = 0; r < 4; ++r) {
            const int rr = lg * 4 + r;
            #pragma unroll
            for (int t4 = 0; t4 < 4; ++t4)
                sP[w][rr * P_PB + t4 * 16 + li] = (__bf16)accs[t4][r];
        }

        bf16x8 pa[2];
        #pragma unroll
        for (int f = 0; f < 2; ++f)
            pa[f] = *(const bf16x8*)&sP[w][li * P_PB + f * 32 + lg * 8];
        #pragma unroll
        for (int t4 = 0; t4 < 4; ++t4) {
            #pragma unroll
            for (int f = 0; f < 2; ++f) {
                bf16x8 vb = *(const bf16x8*)&sVt[(t4 * 16 + li) * VT_P + f * 32 + lg * 8];
                acco[t4] = MFMA_BF16(pa[f], vb, acco[t4]);
            }
        }
    }

    {
        const int qrow0 = qt * 64 + w * 16;
        #pragma unroll
        for (int r = 0; r < 4; ++r) {
            const int rr = lg * 4 + r;
            const float inv = 1.f / lval[r];
            #pragma unroll
            for (int t4 = 0; t4 < 4; ++t4)
                Og[(size_t)(qrow0 + rr) * DH + t4 * 16 + li] = acco[t4][r] * inv;
        }
    }
}

extern "C" void kernel_launch(void* const* d_in, const int* in_sizes, int n_in,
                              void* d_out, int out_size, void* d_ws, size_t ws_size,
                              hipStream_t stream) {
    const float* Q = (const float*)d_in[0];
    const float* K = (const float*)d_in[1];
    const float* V = (const float*)d_in[2];
    float* O = (float*)d_out;
    if (ws_size >= WS_NEED) {
        prep_kernel<<<dim3(4096), dim3(256), 0, stream>>>(K, V, (unsigned char*)d_ws);
        attn_main<<<dim3(2048), dim3(256), 0, stream>>>(Q, (const unsigned char*)d_ws, O);
    } else {
        attn_fwd_kernel<<<dim3(2048), dim3(256), 0, stream>>>(Q, K, V, O);
    }
}